// Round 1
// baseline (83.845 us; speedup 1.0000x reference)
//
#include <hip/hip_runtime.h>

// IntraConsistencyLoss, closed-form reduction version.
//
// Reference math (per row, g binary in {0,1}, P = #positives, Q = W-P):
//   M1 sums to P^2-P, M2 to 2PQ, M3 to Q^2-Q  (diagonal always excluded or 0)
//   S1 = sum over (pos,pos) ordered pairs of |h_i-h_j|
//   S2 = sum over mixed ordered pairs
//   S3 = sum over (neg,neg) ordered pairs
//   loss = S1/(P^2-P+1) + 1 - S2/(2PQ+1) + S3/(Q^2-Q+1)
// Output = loss_a + loss_s + loss_e  (ALPHA = 1)

constexpr int NROW = 256;
constexpr int W    = 512;
constexpr int NT   = 256;   // threads per block; each thread owns 2 i-values

__global__ __launch_bounds__(NT) void icl_kernel(
    const float* __restrict__ a_gt,   const float* __restrict__ s_gt,
    const float* __restrict__ e_gt,   const float* __restrict__ a_heat,
    const float* __restrict__ s_heat, const float* __restrict__ e_heat,
    float* __restrict__ out)
{
    const int row = blockIdx.x;   // 0..255
    const int t   = blockIdx.y;   // 0..2  (a / s / e)

    const float* gt   = (t == 0) ? a_gt   : (t == 1) ? s_gt   : e_gt;
    const float* heat = (t == 0) ? a_heat : (t == 1) ? s_heat : e_heat;
    gt   += (size_t)row * W;
    heat += (size_t)row * W;

    __shared__ float2 sh[W];        // interleaved {h, g} -> one ds_read_b64/j
    __shared__ float  wred[4][NT / 64];

    const int tid = threadIdx.x;

    // ---- stage row into LDS, count positives on the fly ----
    float my_g = 0.f;
    #pragma unroll
    for (int k = tid; k < W; k += NT) {
        float h = heat[k];
        float g = gt[k];
        sh[k] = make_float2(h, g);
        my_g += g;                  // each element staged exactly once
    }
    __syncthreads();

    // ---- each thread owns i0 = tid, i1 = tid + NT; share every j-read ----
    const float2 v0 = sh[tid];
    const float2 v1 = sh[tid + NT];
    const float hi0 = v0.x, gi0 = v0.y;
    const float hi1 = v1.x, gi1 = v1.y;

    float sa0 = 0.f, sp0 = 0.f;     // sum_all / sum_pos for i0
    float sa1 = 0.f, sp1 = 0.f;     // and for i1
    #pragma unroll 8
    for (int j = 0; j < W; ++j) {
        float2 v  = sh[j];          // broadcast read, conflict-free
        float  d0 = fabsf(hi0 - v.x);
        float  d1 = fabsf(hi1 - v.x);
        sa0 += d0;
        sa1 += d1;
        sp0  = fmaf(v.y, d0, sp0);
        sp1  = fmaf(v.y, d1, sp1);
    }

    // ---- route into S1/S2/S3 by g_i (diagonal contributes |h_i-h_i| = 0) ----
    float s1 = 0.f, s2 = 0.f, s3 = 0.f;
    {
        const float sn0 = sa0 - sp0;
        if (gi0 > 0.5f) { s1 += sp0; s2 += sn0; }
        else            { s2 += sp0; s3 += sn0; }
        const float sn1 = sa1 - sp1;
        if (gi1 > 0.5f) { s1 += sp1; s2 += sn1; }
        else            { s2 += sp1; s3 += sn1; }
    }

    // ---- block reduction: 4 scalars (s1, s2, s3, P) ----
    float vals[4] = { s1, s2, s3, my_g };
    #pragma unroll
    for (int off = 32; off >= 1; off >>= 1) {
        #pragma unroll
        for (int q = 0; q < 4; ++q)
            vals[q] += __shfl_down(vals[q], off, 64);
    }
    const int lane = tid & 63;
    const int wv   = tid >> 6;
    if (lane == 0) {
        #pragma unroll
        for (int q = 0; q < 4; ++q) wred[q][wv] = vals[q];
    }
    __syncthreads();

    if (tid == 0) {
        float S1 = 0.f, S2 = 0.f, S3 = 0.f, P = 0.f;
        #pragma unroll
        for (int w = 0; w < NT / 64; ++w) {
            S1 += wred[0][w];
            S2 += wred[1][w];
            S3 += wred[2][w];
            P  += wred[3][w];
        }
        // P is a sum of exact 0.0/1.0 floats, <= 512 -> exact integer in fp32
        const float Q  = (float)W - P;
        const float p1 = P * P - P + 1.0f;          // exact (<= 512^2)
        const float p2 = 2.0f * P * Q + 1.0f;
        const float p3 = Q * Q - Q + 1.0f;
        const float loss = S1 / p1 + 1.0f - S2 / p2 + S3 / p3;
        atomicAdd(&out[row], loss);                 // 3 adders per row (a/s/e)
    }
}

extern "C" void kernel_launch(void* const* d_in, const int* in_sizes, int n_in,
                              void* d_out, int out_size, void* d_ws, size_t ws_size,
                              hipStream_t stream) {
    const float* a_gt   = (const float*)d_in[0];
    const float* s_gt   = (const float*)d_in[1];
    const float* e_gt   = (const float*)d_in[2];
    const float* a_heat = (const float*)d_in[3];
    const float* s_heat = (const float*)d_in[4];
    const float* e_heat = (const float*)d_in[5];
    float* out = (float*)d_out;

    // d_out is poisoned with 0xAA before every timed call; zero it for atomics.
    hipMemsetAsync(out, 0, NROW * sizeof(float), stream);

    dim3 grid(NROW, 3);
    icl_kernel<<<grid, NT, 0, stream>>>(a_gt, s_gt, e_gt,
                                        a_heat, s_heat, e_heat, out);
}